// Round 4
// baseline (26.075 us; speedup 1.0000x reference)
//
#include <hip/hip_runtime.h>
#include <hip/hip_bf16.h>
#include <math.h>

// Problem constants (match reference)
#define V1N   225
#define V2N   224
#define RANK  64
#define DDIM  32          // D1 == D2 == 32
#define ROWE  (RANK*DDIM) // 2048 elements per table row (4KB bf16)

typedef __bf16  bf16x8 __attribute__((ext_vector_type(8)));
typedef float  f32x16 __attribute__((ext_vector_type(16)));
typedef float  f32x4  __attribute__((ext_vector_type(4)));
typedef int    i32x4  __attribute__((ext_vector_type(4)));

// ---------------------------------------------------------------------------
// Prep: dequantize int8 cores into bf16 tables in d_ws. ONE ROW PER WAVE
// (449 rows -> 113 blocks of 4 waves; <=1 block/CU -> fully parallel).
// Dst layout per row: [s(4)][d(32)][rr(16)], r = s*16+rr, so each MFMA
// fragment load in tt_main is one contiguous 16B and each wave fragment
// load instruction covers a dense 1KB.
// core1 gets scale*(q-zp)*cos(phase[r]); core2 gets scale*(q-zp).
// ---------------------------------------------------------------------------
__global__ __launch_bounds__(256) void prep_tables(
    const int* __restrict__ c1q, const int* __restrict__ c2q,
    const float* __restrict__ s1p, const float* __restrict__ z1p,
    const float* __restrict__ s2p, const float* __restrict__ z2p,
    const float* __restrict__ phase,
    __bf16* __restrict__ t1, __bf16* __restrict__ t2)
{
    __shared__ float cosv[RANK];
    __shared__ float lds[4][64 * 33];   // per-wave slab, padded

    int t = threadIdx.x;
    if (t < RANK) cosv[t] = cosf(phase[t]);
    __syncthreads();

    int w    = t >> 6;
    int lane = t & 63;
    int v    = blockIdx.x * 4 + w;
    if (v >= V1N + V2N) return;

    bool is1 = (v < V1N);
    const int* src; __bf16* dst; float sc, zp;
    if (is1) { src = c1q + (size_t)v * ROWE;            dst = t1 + (size_t)v * ROWE;  sc = *s1p; zp = *z1p; }
    else     { int u = v - V1N; src = c2q + (size_t)u * ROWE; dst = t2 + (size_t)u * ROWE; sc = *s2p; zp = *z2p; }

    float* L = lds[w];
    #pragma unroll
    for (int p = 0; p < 4; ++p) {
        // coalesced: 8 consecutive int32 per lane -> 2KB dense per pass
        i32x4 q0 = reinterpret_cast<const i32x4*>(src)[p * 128 + lane * 2];
        i32x4 q1 = reinterpret_cast<const i32x4*>(src)[p * 128 + lane * 2 + 1];
        #pragma unroll
        for (int j = 0; j < 8; ++j) {
            int e = p * 512 + lane * 8 + j;   // src layout [r(64)][d(32)]
            int q = (j < 4) ? q0[j & 3] : q1[j & 3];
            float val = ((float)q - zp) * sc;
            if (is1) val *= cosv[e >> 5];
            L[(e >> 5) * 33 + (e & 31)] = val; // scalar writes, <=2-way alias
        }
    }
    // same-wave producer/consumer: per-wave LDS ordering + lgkmcnt suffices
    #pragma unroll
    for (int h = 0; h < 4; ++h) {
        // dst elem = h*512 + lane*8 + j  ->  s=h, d=lane>>1, rr=(lane&1)*8+j
        int d   = lane >> 1;
        int rr0 = (lane & 1) * 8;
        bf16x8 o8;
        #pragma unroll
        for (int j = 0; j < 8; ++j) {
            int r = h * 16 + rr0 + j;
            o8[j] = (__bf16)L[r * 33 + d];
        }
        *reinterpret_cast<bf16x8*>(dst + h * 512 + lane * 8) = o8;
    }
}

// ---------------------------------------------------------------------------
// Main: TWO tokens per wave. Per token: 4x mfma_f32_32x32x16_bf16 over
// rank=64 with swapped operands (A=c2, B=c1), wave-local LDS transpose
// (no __syncthreads -- same-wave staging, two slabs so no WAR), then
// fully dense stores: lane i stores 16B at tile_base + i*16B -> 1KB
// contiguous per store instruction.
// C/D layout (HW-verified): col=lane&31, row=(reg&3)+8*(reg>>2)+4*(lane>>5).
// ---------------------------------------------------------------------------
__global__ __launch_bounds__(256) void tt_main(
    const int* __restrict__ ids,
    const __bf16* __restrict__ t1, const __bf16* __restrict__ t2,
    float* __restrict__ out, int n_tok)
{
    __shared__ float tile[4][2][32 * 33];

    int w    = threadIdx.x >> 6;
    int lane = threadIdx.x & 63;
    int m = lane & 31;   // d1
    int g = lane >> 5;
    int tok0 = ((blockIdx.x << 2) + w) * 2;
    int tok1 = tok0 + 1;
    bool act0 = (tok0 < n_tok);
    bool act1 = (tok1 < n_tok);

    bf16x8 a0[4], b0[4], a1[4], b1[4];

    if (act0) {
        unsigned id = (unsigned)ids[tok0];
        unsigned i1 = id / 224u; if (i1 > (unsigned)(V1N - 1)) i1 = V1N - 1;
        unsigned i2 = id % 224u;
        const __bf16* ab = t2 + (size_t)i2 * ROWE + m * 16 + g * 8;
        const __bf16* bb = t1 + (size_t)i1 * ROWE + m * 16 + g * 8;
        #pragma unroll
        for (int s = 0; s < 4; ++s) {
            a0[s] = *reinterpret_cast<const bf16x8*>(ab + s * 512);
            b0[s] = *reinterpret_cast<const bf16x8*>(bb + s * 512);
        }
    }
    if (act1) {
        unsigned id = (unsigned)ids[tok1];
        unsigned i1 = id / 224u; if (i1 > (unsigned)(V1N - 1)) i1 = V1N - 1;
        unsigned i2 = id % 224u;
        const __bf16* ab = t2 + (size_t)i2 * ROWE + m * 16 + g * 8;
        const __bf16* bb = t1 + (size_t)i1 * ROWE + m * 16 + g * 8;
        #pragma unroll
        for (int s = 0; s < 4; ++s) {
            a1[s] = *reinterpret_cast<const bf16x8*>(ab + s * 512);
            b1[s] = *reinterpret_cast<const bf16x8*>(bb + s * 512);
        }
    }

    // ---- token 0 ----
    if (act0) {
        f32x16 acc;
        #pragma unroll
        for (int i = 0; i < 16; ++i) acc[i] = 0.0f;
        #pragma unroll
        for (int s = 0; s < 4; ++s)
            acc = __builtin_amdgcn_mfma_f32_32x32x16_bf16(a0[s], b0[s], acc, 0, 0, 0);

        float* tp = tile[w][0];
        #pragma unroll
        for (int q = 0; q < 4; ++q)
            #pragma unroll
            for (int j = 0; j < 4; ++j)
                tp[m * 33 + 8 * q + 4 * g + j] = acc[4 * q + j];

        float* o = out + (size_t)tok0 * 1024;
        #pragma unroll
        for (int p = 0; p < 4; ++p) {
            int d1 = p * 8 + (lane >> 3);
            int d2 = (lane & 7) * 4;
            f32x4 v = { tp[d1 * 33 + d2 + 0], tp[d1 * 33 + d2 + 1],
                        tp[d1 * 33 + d2 + 2], tp[d1 * 33 + d2 + 3] };
            *reinterpret_cast<f32x4*>(o + p * 256 + lane * 4) = v;
        }
    }

    // ---- token 1 ----
    if (act1) {
        f32x16 acc;
        #pragma unroll
        for (int i = 0; i < 16; ++i) acc[i] = 0.0f;
        #pragma unroll
        for (int s = 0; s < 4; ++s)
            acc = __builtin_amdgcn_mfma_f32_32x32x16_bf16(a1[s], b1[s], acc, 0, 0, 0);

        float* tp = tile[w][1];
        #pragma unroll
        for (int q = 0; q < 4; ++q)
            #pragma unroll
            for (int j = 0; j < 4; ++j)
                tp[m * 33 + 8 * q + 4 * g + j] = acc[4 * q + j];

        float* o = out + (size_t)tok1 * 1024;
        #pragma unroll
        for (int p = 0; p < 4; ++p) {
            int d1 = p * 8 + (lane >> 3);
            int d2 = (lane & 7) * 4;
            f32x4 v = { tp[d1 * 33 + d2 + 0], tp[d1 * 33 + d2 + 1],
                        tp[d1 * 33 + d2 + 2], tp[d1 * 33 + d2 + 3] };
            *reinterpret_cast<f32x4*>(o + p * 256 + lane * 4) = v;
        }
    }
}

// ---------------------------------------------------------------------------
// Fallback (if d_ws is too small): fused on-the-fly dequant + MFMA.
// ---------------------------------------------------------------------------
__global__ __launch_bounds__(256) void tt_fused(
    const int* __restrict__ ids,
    const int* __restrict__ c1q, const int* __restrict__ c2q,
    const float* __restrict__ s1p, const float* __restrict__ z1p,
    const float* __restrict__ s2p, const float* __restrict__ z2p,
    const float* __restrict__ phase,
    float* __restrict__ out, int n_tok)
{
    __shared__ float cosv[RANK];
    if (threadIdx.x < RANK) cosv[threadIdx.x] = cosf(phase[threadIdx.x]);
    __syncthreads();

    int wave = (blockIdx.x << 2) + (threadIdx.x >> 6);
    if (wave >= n_tok) return;
    int lane = threadIdx.x & 63;
    int m = lane & 31;
    int g = lane >> 5;

    float s1 = *s1p, z1 = *z1p, s2 = *s2p, z2 = *z2p;

    unsigned id = (unsigned)ids[wave];
    unsigned i1 = id / 224u; if (i1 > (unsigned)(V1N - 1)) i1 = V1N - 1;
    unsigned i2 = id % 224u;

    const int* a_src = c2q + (size_t)i2 * ROWE + m;   // A = c2, [r][d] stride 32
    const int* b_src = c1q + (size_t)i1 * ROWE + m;   // B = c1

    f32x16 acc;
    #pragma unroll
    for (int i = 0; i < 16; ++i) acc[i] = 0.0f;

    #pragma unroll
    for (int s = 0; s < 4; ++s) {
        bf16x8 a, b;
        #pragma unroll
        for (int j = 0; j < 8; ++j) {
            int r = s * 16 + g * 8 + j;
            a[j] = (__bf16)((((float)a_src[r * 32]) - z2) * s2);
            b[j] = (__bf16)((((float)b_src[r * 32]) - z1) * s1 * cosv[r]);
        }
        acc = __builtin_amdgcn_mfma_f32_32x32x16_bf16(a, b, acc, 0, 0, 0);
    }

    float* o = out + (size_t)wave * 1024 + m * 32 + g * 4;
    #pragma unroll
    for (int q = 0; q < 4; ++q) {
        f32x4 v = { acc[4 * q + 0], acc[4 * q + 1], acc[4 * q + 2], acc[4 * q + 3] };
        *reinterpret_cast<f32x4*>(o + 8 * q) = v;
    }
}

extern "C" void kernel_launch(void* const* d_in, const int* in_sizes, int n_in,
                              void* d_out, int out_size, void* d_ws, size_t ws_size,
                              hipStream_t stream) {
    const int*   ids = (const int*)d_in[0];
    const int*   c1q = (const int*)d_in[1];   // int8 values delivered as int32
    const float* s1  = (const float*)d_in[2];
    const float* z1  = (const float*)d_in[3];
    const int*   c2q = (const int*)d_in[4];
    const float* s2  = (const float*)d_in[5];
    const float* z2  = (const float*)d_in[6];
    const float* ph  = (const float*)d_in[7];
    float* out = (float*)d_out;

    int n_tok = in_sizes[0];                  // 16384
    int grid  = (n_tok + 7) / 8;              // 4 waves/block, 2 tokens/wave

    size_t need = (size_t)(V1N + V2N) * ROWE * sizeof(__bf16);  // ~1.84 MB
    if (ws_size >= need) {
        __bf16* t1 = (__bf16*)d_ws;
        __bf16* t2 = t1 + (size_t)V1N * ROWE;
        prep_tables<<<(V1N + V2N + 3) / 4, 256, 0, stream>>>(c1q, c2q, s1, z1, s2, z2, ph, t1, t2);
        tt_main<<<grid, 256, 0, stream>>>(ids, t1, t2, out, n_tok);
    } else {
        int fgrid = (n_tok + 3) / 4;
        tt_fused<<<fgrid, 256, 0, stream>>>(ids, c1q, c2q, s1, z1, s2, z2, ph, out, n_tok);
    }
}

// Round 5
// 25.937 us; speedup vs baseline: 1.0053x; 1.0053x over previous
//
#include <hip/hip_runtime.h>
#include <hip/hip_bf16.h>
#include <math.h>

// Problem constants (match reference)
#define V1N   225
#define V2N   224
#define RANK  64
#define DDIM  32          // D1 == D2 == 32
#define ROWE  (RANK*DDIM) // 2048 elements per table row (4KB bf16)
#define TPW   8           // tokens per wave (sequential output range)

typedef __bf16  bf16x8 __attribute__((ext_vector_type(8)));
typedef float  f32x16 __attribute__((ext_vector_type(16)));
typedef float  f32x4  __attribute__((ext_vector_type(4)));
typedef int    i32x4  __attribute__((ext_vector_type(4)));

// ---------------------------------------------------------------------------
// Prep: dequantize int8 cores into bf16 tables in d_ws. One row per wave
// (113 blocks x 4 waves, fully parallel). Dst layout per row:
// [s(4)][d(32)][rr(16)], r = s*16+rr -> each MFMA fragment load in tt_main
// is one contiguous 16B, and a wave's fragment load covers a dense 1KB.
// core1 gets scale*(q-zp)*cos(phase[r]); core2 gets scale*(q-zp).
// ---------------------------------------------------------------------------
__global__ __launch_bounds__(256) void prep_tables(
    const int* __restrict__ c1q, const int* __restrict__ c2q,
    const float* __restrict__ s1p, const float* __restrict__ z1p,
    const float* __restrict__ s2p, const float* __restrict__ z2p,
    const float* __restrict__ phase,
    __bf16* __restrict__ t1, __bf16* __restrict__ t2)
{
    __shared__ float cosv[RANK];
    __shared__ float lds[4][64 * 33];   // per-wave slab, padded

    int t = threadIdx.x;
    if (t < RANK) cosv[t] = cosf(phase[t]);
    __syncthreads();

    int w    = t >> 6;
    int lane = t & 63;
    int v    = blockIdx.x * 4 + w;
    if (v >= V1N + V2N) return;

    bool is1 = (v < V1N);
    const int* src; __bf16* dst; float sc, zp;
    if (is1) { src = c1q + (size_t)v * ROWE;            dst = t1 + (size_t)v * ROWE;  sc = *s1p; zp = *z1p; }
    else     { int u = v - V1N; src = c2q + (size_t)u * ROWE; dst = t2 + (size_t)u * ROWE; sc = *s2p; zp = *z2p; }

    float* L = lds[w];
    #pragma unroll
    for (int p = 0; p < 4; ++p) {
        i32x4 q0 = reinterpret_cast<const i32x4*>(src)[p * 128 + lane * 2];
        i32x4 q1 = reinterpret_cast<const i32x4*>(src)[p * 128 + lane * 2 + 1];
        #pragma unroll
        for (int j = 0; j < 8; ++j) {
            int e = p * 512 + lane * 8 + j;   // src layout [r(64)][d(32)]
            int q = (j < 4) ? q0[j & 3] : q1[j & 3];
            float val = ((float)q - zp) * sc;
            if (is1) val *= cosv[e >> 5];
            L[(e >> 5) * 33 + (e & 31)] = val;
        }
    }
    // same-wave producer/consumer: per-wave in-order DS + lgkmcnt suffices
    #pragma unroll
    for (int h = 0; h < 4; ++h) {
        int d   = lane >> 1;
        int rr0 = (lane & 1) * 8;
        bf16x8 o8;
        #pragma unroll
        for (int j = 0; j < 8; ++j) {
            int r = h * 16 + rr0 + j;
            o8[j] = (__bf16)L[r * 33 + d];
        }
        *reinterpret_cast<bf16x8*>(dst + h * 512 + lane * 8) = o8;
    }
}

// ---------------------------------------------------------------------------
// Main: 8 consecutive tokens per wave (32KB sequential output per wave),
// 1-token-deep register prefetch: next token's 8 fragment loads are issued
// before the current token's MFMA/LDS/store phase, hiding L2 latency.
// Swapped operands (A=c2, B=c1); wave-local padded-LDS transpose (two slabs,
// no barrier needed); fully dense stores (lane i -> tile_base + i*16B).
// C/D layout (HW-verified): col=lane&31, row=(reg&3)+8*(reg>>2)+4*(lane>>5).
// ---------------------------------------------------------------------------
__global__ __launch_bounds__(256) void tt_main(
    const int* __restrict__ ids,
    const __bf16* __restrict__ t1, const __bf16* __restrict__ t2,
    float* __restrict__ out, int n_tok)
{
    __shared__ float tile[4][2][32 * 33];

    int w    = threadIdx.x >> 6;
    int lane = threadIdx.x & 63;
    int m = lane & 31;   // d1
    int g = lane >> 5;
    int t0 = (blockIdx.x * 4 + w) * TPW;
    if (t0 >= n_tok) return;

    // 32-bit row offsets (element units) — keeps VGPR use low
    int aoff[TPW], boff[TPW];
    #pragma unroll
    for (int i = 0; i < TPW; ++i) {
        int t = t0 + i;
        unsigned id = (unsigned)ids[t < n_tok ? t : (n_tok - 1)];
        unsigned i1 = id / 224u; if (i1 > (unsigned)(V1N - 1)) i1 = V1N - 1;
        unsigned i2 = id % 224u;
        aoff[i] = (int)(i2 * ROWE);
        boff[i] = (int)(i1 * ROWE);
    }
    const __bf16* abase = t2 + m * 16 + g * 8;   // A = c2
    const __bf16* bbase = t1 + m * 16 + g * 8;   // B = c1

    bf16x8 aC[4], bC[4];
    #pragma unroll
    for (int s = 0; s < 4; ++s) {
        aC[s] = *reinterpret_cast<const bf16x8*>(abase + aoff[0] + s * 512);
        bC[s] = *reinterpret_cast<const bf16x8*>(bbase + boff[0] + s * 512);
    }

    #pragma unroll
    for (int k = 0; k < TPW; ++k) {
        // prefetch next token's fragments (issued before this token's compute)
        bf16x8 aN[4], bN[4];
        if (k + 1 < TPW) {
            #pragma unroll
            for (int s = 0; s < 4; ++s) {
                aN[s] = *reinterpret_cast<const bf16x8*>(abase + aoff[k + 1] + s * 512);
                bN[s] = *reinterpret_cast<const bf16x8*>(bbase + boff[k + 1] + s * 512);
            }
        }

        f32x16 acc;
        #pragma unroll
        for (int i = 0; i < 16; ++i) acc[i] = 0.0f;
        #pragma unroll
        for (int s = 0; s < 4; ++s)
            acc = __builtin_amdgcn_mfma_f32_32x32x16_bf16(aC[s], bC[s], acc, 0, 0, 0);

        // stage tile[d1][d2]: d1 = m, d2 = 8*q + 4*g + j  (2-way alias max)
        float* tp = tile[w][k & 1];
        #pragma unroll
        for (int q = 0; q < 4; ++q)
            #pragma unroll
            for (int j = 0; j < 4; ++j)
                tp[m * 33 + 8 * q + 4 * g + j] = acc[4 * q + j];

        int tok = t0 + k;
        if (tok < n_tok) {
            float* o = out + (size_t)tok * 1024;
            #pragma unroll
            for (int p = 0; p < 4; ++p) {
                int d1 = p * 8 + (lane >> 3);
                int d2 = (lane & 7) * 4;
                f32x4 v = { tp[d1 * 33 + d2 + 0], tp[d1 * 33 + d2 + 1],
                            tp[d1 * 33 + d2 + 2], tp[d1 * 33 + d2 + 3] };
                *reinterpret_cast<f32x4*>(o + p * 256 + lane * 4) = v;
            }
        }

        if (k + 1 < TPW) {
            #pragma unroll
            for (int s = 0; s < 4; ++s) { aC[s] = aN[s]; bC[s] = bN[s]; }
        }
    }
}

// ---------------------------------------------------------------------------
// Fallback (if d_ws is too small): fused on-the-fly dequant + MFMA.
// ---------------------------------------------------------------------------
__global__ __launch_bounds__(256) void tt_fused(
    const int* __restrict__ ids,
    const int* __restrict__ c1q, const int* __restrict__ c2q,
    const float* __restrict__ s1p, const float* __restrict__ z1p,
    const float* __restrict__ s2p, const float* __restrict__ z2p,
    const float* __restrict__ phase,
    float* __restrict__ out, int n_tok)
{
    __shared__ float cosv[RANK];
    if (threadIdx.x < RANK) cosv[threadIdx.x] = cosf(phase[threadIdx.x]);
    __syncthreads();

    int wave = (blockIdx.x << 2) + (threadIdx.x >> 6);
    if (wave >= n_tok) return;
    int lane = threadIdx.x & 63;
    int m = lane & 31;
    int g = lane >> 5;

    float s1 = *s1p, z1 = *z1p, s2 = *s2p, z2 = *z2p;

    unsigned id = (unsigned)ids[wave];
    unsigned i1 = id / 224u; if (i1 > (unsigned)(V1N - 1)) i1 = V1N - 1;
    unsigned i2 = id % 224u;

    const int* a_src = c2q + (size_t)i2 * ROWE + m;   // A = c2, [r][d] stride 32
    const int* b_src = c1q + (size_t)i1 * ROWE + m;   // B = c1

    f32x16 acc;
    #pragma unroll
    for (int i = 0; i < 16; ++i) acc[i] = 0.0f;

    #pragma unroll
    for (int s = 0; s < 4; ++s) {
        bf16x8 a, b;
        #pragma unroll
        for (int j = 0; j < 8; ++j) {
            int r = s * 16 + g * 8 + j;
            a[j] = (__bf16)((((float)a_src[r * 32]) - z2) * s2);
            b[j] = (__bf16)((((float)b_src[r * 32]) - z1) * s1 * cosv[r]);
        }
        acc = __builtin_amdgcn_mfma_f32_32x32x16_bf16(a, b, acc, 0, 0, 0);
    }

    float* o = out + (size_t)wave * 1024 + m * 32 + g * 4;
    #pragma unroll
    for (int q = 0; q < 4; ++q) {
        f32x4 v = { acc[4 * q + 0], acc[4 * q + 1], acc[4 * q + 2], acc[4 * q + 3] };
        *reinterpret_cast<f32x4*>(o + 8 * q) = v;
    }
}

extern "C" void kernel_launch(void* const* d_in, const int* in_sizes, int n_in,
                              void* d_out, int out_size, void* d_ws, size_t ws_size,
                              hipStream_t stream) {
    const int*   ids = (const int*)d_in[0];
    const int*   c1q = (const int*)d_in[1];   // int8 values delivered as int32
    const float* s1  = (const float*)d_in[2];
    const float* z1  = (const float*)d_in[3];
    const int*   c2q = (const int*)d_in[4];
    const float* s2  = (const float*)d_in[5];
    const float* z2  = (const float*)d_in[6];
    const float* ph  = (const float*)d_in[7];
    float* out = (float*)d_out;

    int n_tok = in_sizes[0];                  // 16384
    int grid  = (n_tok + 4 * TPW - 1) / (4 * TPW);   // 4 waves/block, 8 tok/wave

    size_t need = (size_t)(V1N + V2N) * ROWE * sizeof(__bf16);  // ~1.84 MB
    if (ws_size >= need) {
        __bf16* t1 = (__bf16*)d_ws;
        __bf16* t2 = t1 + (size_t)V1N * ROWE;
        prep_tables<<<(V1N + V2N + 3) / 4, 256, 0, stream>>>(c1q, c2q, s1, z1, s2, z2, ph, t1, t2);
        tt_main<<<grid, 256, 0, stream>>>(ids, t1, t2, out, n_tok);
    } else {
        int fgrid = (n_tok + 3) / 4;
        tt_fused<<<fgrid, 256, 0, stream>>>(ids, c1q, c2q, s1, z1, s2, z2, ph, out, n_tok);
    }
}

// Round 6
// 22.548 us; speedup vs baseline: 1.1564x; 1.1503x over previous
//
#include <hip/hip_runtime.h>
#include <hip/hip_bf16.h>
#include <math.h>

// Problem constants (match reference)
#define V1N   225
#define V2N   224
#define RANK  64
#define DDIM  32          // D1 == D2 == 32
#define ROWE  (RANK*DDIM) // 2048 elements per table row

typedef __bf16  bf16x8 __attribute__((ext_vector_type(8)));
typedef float  f32x16 __attribute__((ext_vector_type(16)));
typedef float  f32x4  __attribute__((ext_vector_type(4)));
typedef int    i32x4  __attribute__((ext_vector_type(4)));

// ---------------------------------------------------------------------------
// Prep: dequantize int8 cores into bf16 tables in d_ws.
// Dst layout per row v: [s(4)][d(32)][rr(16)]  where r = s*16 + rr,
// so each MFMA fragment load in the main kernel is one contiguous 16B.
// core1 gets scale*(q-zp)*cos(phase[r]); core2 gets scale*(q-zp).
// ---------------------------------------------------------------------------
__global__ __launch_bounds__(256) void prep_tables(
    const int* __restrict__ c1q, const int* __restrict__ c2q,
    const float* __restrict__ s1p, const float* __restrict__ z1p,
    const float* __restrict__ s2p, const float* __restrict__ z2p,
    const float* __restrict__ phase,
    __bf16* __restrict__ t1, __bf16* __restrict__ t2)
{
    __shared__ float lds[64 * 33];   // [r][d] padded, 2-way max bank alias
    __shared__ float cosv[RANK];

    int v = blockIdx.x;
    bool is1 = (v < V1N);
    const int* src;
    __bf16* dst;
    float sc, zp;
    if (is1) { src = c1q + v * ROWE;            dst = t1 + (size_t)v * ROWE;  sc = *s1p; zp = *z1p; }
    else     { int u = v - V1N; src = c2q + u * ROWE; dst = t2 + (size_t)u * ROWE; sc = *s2p; zp = *z2p; }

    int t = threadIdx.x;
    if (is1 && t < RANK) cosv[t] = cosf(phase[t]);
    __syncthreads();

    // coalesced read: 8 consecutive int32 per thread (2x int4)
    i32x4 w0 = reinterpret_cast<const i32x4*>(src)[t * 2];
    i32x4 w1 = reinterpret_cast<const i32x4*>(src)[t * 2 + 1];
    #pragma unroll
    for (int j = 0; j < 8; ++j) {
        int e = t * 8 + j;                 // src layout [r(64)][d(32)]
        int q = (j < 4) ? w0[j & 3] : w1[j & 3];
        float val = ((float)q - zp) * sc;
        if (is1) val *= cosv[e >> 5];
        lds[(e >> 5) * 33 + (e & 31)] = val;
    }
    __syncthreads();

    // dst-ordered write: thread t produces dst[t*8 .. t*8+8)
    // e_dst = s*512 + d*16 + rr  ->  s=t>>6, d=(t>>1)&31, rr0=(t&1)*8
    int s   = t >> 6;
    int d   = (t >> 1) & 31;
    int rr0 = (t & 1) * 8;
    bf16x8 o8;
    #pragma unroll
    for (int j = 0; j < 8; ++j) {
        int r = s * 16 + rr0 + j;
        o8[j] = (__bf16)lds[r * 33 + d];
    }
    *reinterpret_cast<bf16x8*>(dst + t * 8) = o8;
}

// ---------------------------------------------------------------------------
// Main: one wave per token. 4x mfma_f32_32x32x16_bf16 over rank=64.
// Swapped operands (A=c2, B=c1): lane owns d1=lane&31, d2=(reg&3)+8*(reg>>2)
// +4*(lane>>5). Stage the 32x32 f32 tile into padded LDS, then write out
// with FULLY DENSE stores: lane i stores 16B at tile_base + i*16B -> 1KB
// contiguous per store instruction. NEW vs R2: stores are NONTEMPORAL --
// dense full-line pattern + nt bypasses L2 allocate/evict double-handling
// (fillBuffer-style streaming) and keeps the bf16 tables L2-resident.
// C/D layout (HW-verified): col=lane&31, row=(reg&3)+8*(reg>>2)+4*(lane>>5).
// ---------------------------------------------------------------------------
__global__ __launch_bounds__(256) void tt_main(
    const int* __restrict__ ids,
    const __bf16* __restrict__ t1, const __bf16* __restrict__ t2,
    float* __restrict__ out, int n_tok)
{
    __shared__ float tile[4][32 * 33];

    int w    = threadIdx.x >> 6;
    int wave = (blockIdx.x << 2) + w;
    int lane = threadIdx.x & 63;
    int m = lane & 31;   // d1
    int g = lane >> 5;
    bool active = (wave < n_tok);

    if (active) {
        unsigned id = (unsigned)ids[wave];
        unsigned i1 = id / 224u; if (i1 > (unsigned)(V1N - 1)) i1 = V1N - 1;
        unsigned i2 = id % 224u;

        const __bf16* a_base = t2 + (size_t)i2 * ROWE + m * 16 + g * 8;  // A = c2
        const __bf16* b_base = t1 + (size_t)i1 * ROWE + m * 16 + g * 8;  // B = c1

        f32x16 acc;
        #pragma unroll
        for (int i = 0; i < 16; ++i) acc[i] = 0.0f;

        #pragma unroll
        for (int s = 0; s < 4; ++s) {
            bf16x8 a = *reinterpret_cast<const bf16x8*>(a_base + s * 512);
            bf16x8 b = *reinterpret_cast<const bf16x8*>(b_base + s * 512);
            acc = __builtin_amdgcn_mfma_f32_32x32x16_bf16(a, b, acc, 0, 0, 0);
        }

        // stage tile[d1][d2] = acc: d1 = m, d2 = 8*(reg>>2) + 4*g + (reg&3)
        float* tp = tile[w];
        #pragma unroll
        for (int q = 0; q < 4; ++q) {
            #pragma unroll
            for (int j = 0; j < 4; ++j) {
                tp[m * 33 + 8 * q + 4 * g + j] = acc[4 * q + j];
            }
        }
    }
    __syncthreads();
    if (active) {
        const float* tp = tile[w];
        float* o = out + (size_t)wave * 1024;
        #pragma unroll
        for (int p = 0; p < 4; ++p) {
            // flat offset = p*256 + lane*4 -> d1 = p*8 + (lane>>3), d2 = (lane&7)*4
            int d1 = p * 8 + (lane >> 3);
            int d2 = (lane & 7) * 4;
            f32x4 v = { tp[d1 * 33 + d2 + 0], tp[d1 * 33 + d2 + 1],
                        tp[d1 * 33 + d2 + 2], tp[d1 * 33 + d2 + 3] };
            __builtin_nontemporal_store(v, reinterpret_cast<f32x4*>(o + p * 256 + lane * 4));
        }
    }
}

// ---------------------------------------------------------------------------
// Fallback (if d_ws is too small): fused on-the-fly dequant + MFMA.
// ---------------------------------------------------------------------------
__global__ __launch_bounds__(256) void tt_fused(
    const int* __restrict__ ids,
    const int* __restrict__ c1q, const int* __restrict__ c2q,
    const float* __restrict__ s1p, const float* __restrict__ z1p,
    const float* __restrict__ s2p, const float* __restrict__ z2p,
    const float* __restrict__ phase,
    float* __restrict__ out, int n_tok)
{
    __shared__ float cosv[RANK];
    if (threadIdx.x < RANK) cosv[threadIdx.x] = cosf(phase[threadIdx.x]);
    __syncthreads();

    int wave = (blockIdx.x << 2) + (threadIdx.x >> 6);
    if (wave >= n_tok) return;
    int lane = threadIdx.x & 63;
    int m = lane & 31;
    int g = lane >> 5;

    float s1 = *s1p, z1 = *z1p, s2 = *s2p, z2 = *z2p;

    unsigned id = (unsigned)ids[wave];
    unsigned i1 = id / 224u; if (i1 > (unsigned)(V1N - 1)) i1 = V1N - 1;
    unsigned i2 = id % 224u;

    const int* a_src = c2q + (size_t)i2 * ROWE + m;   // A = c2, [r][d] stride 32
    const int* b_src = c1q + (size_t)i1 * ROWE + m;   // B = c1

    f32x16 acc;
    #pragma unroll
    for (int i = 0; i < 16; ++i) acc[i] = 0.0f;

    #pragma unroll
    for (int s = 0; s < 4; ++s) {
        bf16x8 a, b;
        #pragma unroll
        for (int j = 0; j < 8; ++j) {
            int r = s * 16 + g * 8 + j;
            a[j] = (__bf16)((((float)a_src[r * 32]) - z2) * s2);
            b[j] = (__bf16)((((float)b_src[r * 32]) - z1) * s1 * cosv[r]);
        }
        acc = __builtin_amdgcn_mfma_f32_32x32x16_bf16(a, b, acc, 0, 0, 0);
    }

    float* o = out + (size_t)wave * 1024 + m * 32 + g * 4;
    #pragma unroll
    for (int q = 0; q < 4; ++q) {
        f32x4 v = { acc[4 * q + 0], acc[4 * q + 1], acc[4 * q + 2], acc[4 * q + 3] };
        __builtin_nontemporal_store(v, reinterpret_cast<f32x4*>(o + 8 * q));
    }
}

extern "C" void kernel_launch(void* const* d_in, const int* in_sizes, int n_in,
                              void* d_out, int out_size, void* d_ws, size_t ws_size,
                              hipStream_t stream) {
    const int*   ids = (const int*)d_in[0];
    const int*   c1q = (const int*)d_in[1];   // int8 values delivered as int32
    const float* s1  = (const float*)d_in[2];
    const float* z1  = (const float*)d_in[3];
    const int*   c2q = (const int*)d_in[4];
    const float* s2  = (const float*)d_in[5];
    const float* z2  = (const float*)d_in[6];
    const float* ph  = (const float*)d_in[7];
    float* out = (float*)d_out;

    int n_tok = in_sizes[0];                  // 16384
    int grid  = (n_tok + 3) / 4;              // 4 waves (tokens) per block

    size_t need = (size_t)(V1N + V2N) * ROWE * sizeof(__bf16);  // ~1.84 MB
    if (ws_size >= need) {
        __bf16* t1 = (__bf16*)d_ws;
        __bf16* t2 = t1 + (size_t)V1N * ROWE;
        prep_tables<<<V1N + V2N, 256, 0, stream>>>(c1q, c2q, s1, z1, s2, z2, ph, t1, t2);
        tt_main<<<grid, 256, 0, stream>>>(ids, t1, t2, out, n_tok);
    } else {
        int fgrid = (n_tok + 3) / 4;
        tt_fused<<<fgrid, 256, 0, stream>>>(ids, c1q, c2q, s1, z1, s2, z2, ph, out, n_tok);
    }
}